// Round 1
// baseline (776.665 us; speedup 1.0000x reference)
//
#include <hip/hip_runtime.h>
#include <hip/hip_bf16.h>
#include <cstdint>
#include <cstddef>

#define HIDDEN 2048
#define INTER  4096
#define EPSQ   1e-5f

typedef int v4i __attribute__((ext_vector_type(4)));

__device__ __forceinline__ void async_ld16(const void* g, void* l) {
  __builtin_amdgcn_global_load_lds((const __attribute__((address_space(1))) void*)g,
                                   (__attribute__((address_space(3))) void*)l, 16, 0, 0);
}

// ---------------- absmean reduction (f64 accumulate, atomic combine) ----------------
__global__ void absmean_kernel(const float* __restrict__ w, size_t n4, double* __restrict__ out) {
  double s = 0.0;
  const float4* w4 = (const float4*)w;
  for (size_t i = blockIdx.x * (size_t)blockDim.x + threadIdx.x; i < n4;
       i += (size_t)gridDim.x * blockDim.x) {
    float4 v = w4[i];
    s += (double)fabsf(v.x) + (double)fabsf(v.y) + (double)fabsf(v.z) + (double)fabsf(v.w);
  }
  #pragma unroll
  for (int o = 32; o; o >>= 1) s += __shfl_down(s, o);
  __shared__ double red[4];
  if ((threadIdx.x & 63) == 0) red[threadIdx.x >> 6] = s;
  __syncthreads();
  if (threadIdx.x == 0) atomicAdd(out, red[0] + red[1] + red[2] + red[3]);
}

// ---------------- weight ternarization: q = clip(round(w/scale), -1, 1) ----------------
__global__ void quantw_kernel(const float* __restrict__ w, size_t n4,
                              const double* __restrict__ sum, double invcnt,
                              int8_t* __restrict__ q) {
  const float scale = (float)fmax(sum[0] * invcnt, (double)EPSQ);
  const float4* w4 = (const float4*)w;
  char4* q4 = (char4*)q;
  for (size_t i = blockIdx.x * (size_t)blockDim.x + threadIdx.x; i < n4;
       i += (size_t)gridDim.x * blockDim.x) {
    float4 v = w4[i];
    char4 c;
    c.x = (signed char)fmaxf(-1.f, fminf(1.f, rintf(v.x / scale)));
    c.y = (signed char)fmaxf(-1.f, fminf(1.f, rintf(v.y / scale)));
    c.z = (signed char)fmaxf(-1.f, fminf(1.f, rintf(v.z / scale)));
    c.w = (signed char)fmaxf(-1.f, fminf(1.f, rintf(v.w / scale)));
    q4[i] = c;
  }
}

// ---------------- FWHT (n = 2^LOGN) + per-token absmax int8 quant ----------------
template <int LOGN>
__global__ void fwht_quant_kernel(const float* __restrict__ X, int8_t* __restrict__ Q,
                                  float* __restrict__ invs) {
  constexpr int N = 1 << LOGN;
  constexpr int E = N / 256;          // elems per thread: 8 (2048) or 16 (4096)
  __shared__ float s[N];
  __shared__ float red[4];
  const int tid = threadIdx.x;
  const size_t t = blockIdx.x;
  const float4* xt = (const float4*)(X + t * (size_t)N);
  #pragma unroll
  for (int u = 0; u < N / 1024; ++u) ((float4*)s)[tid + u * 256] = xt[tid + u * 256];
  __syncthreads();
  #pragma unroll
  for (int st = 0; st < LOGN; ++st) {
    const int h = 1 << st;
    #pragma unroll
    for (int u = 0; u < N / 512; ++u) {
      const int p = tid + u * 256;                       // pair index in [0, N/2)
      const int i = ((p >> st) << (st + 1)) | (p & (h - 1));
      const float a = s[i], b = s[i + h];
      s[i] = a + b;
      s[i + h] = a - b;
    }
    __syncthreads();
  }
  const float c = (LOGN == 11) ? 0.022097086912079608f : 0.015625f;  // 1/sqrt(N)
  float r[E];
  float mx = 0.f;
  #pragma unroll
  for (int e = 0; e < E; ++e) {
    float v = s[tid * E + e] * c;
    r[e] = v;
    mx = fmaxf(mx, fabsf(v));
  }
  #pragma unroll
  for (int o = 32; o; o >>= 1) mx = fmaxf(mx, __shfl_down(mx, o));
  if ((tid & 63) == 0) red[tid >> 6] = mx;
  __syncthreads();
  mx = fmaxf(fmaxf(red[0], red[1]), fmaxf(red[2], red[3]));
  mx = fmaxf(mx, EPSQ);
  const float scale = 127.0f / mx;
  if (tid == 0) invs[t] = mx / 127.0f;
  alignas(16) int8_t qv[E];
  #pragma unroll
  for (int e = 0; e < E; ++e) {
    float q = rintf(r[e] * scale);
    q = fmaxf(-127.f, fminf(127.f, q));
    qv[e] = (int8_t)q;
  }
  if constexpr (E == 8)
    *(int2*)(Q + t * (size_t)N + tid * E) = *(const int2*)qv;
  else
    *(int4*)(Q + t * (size_t)N + tid * E) = *(const int4*)qv;
}

// ---------------- int8 GEMM: C[t,n] = epilogue( sum_k A[t,k]*B[n,k] ) ----------------
// 128x128 tile, BK=64 bytes, 256 threads = 4 waves (2x2), each wave 64x64 via 4x4 mfma 16x16x64.
template <bool RELU2>
__global__ void gemm_i8_kernel(const int8_t* __restrict__ A, const int8_t* __restrict__ B,
                               float* __restrict__ C, const float* __restrict__ invs,
                               const double* __restrict__ wsum, double invcnt,
                               int N, int K) {
  __shared__ int8_t As[128 * 64];
  __shared__ int8_t Bs[128 * 64];
  const int tid = threadIdx.x;
  const int lane = tid & 63, wave = tid >> 6;
  const int wr = wave >> 1, wc = wave & 1;
  const int m0 = blockIdx.y * 128, n0 = blockIdx.x * 128;

  v4i acc[4][4] = {};

  // staging: chunk c covers (row = c>>2, 16B col chunk = c&3); thread does c = tid and tid+256
  const int row = tid >> 2;
  const int colb = (tid & 3) * 16;
  const int8_t* gA0 = A + (size_t)(m0 + row) * K + colb;
  const int8_t* gA1 = A + (size_t)(m0 + row + 64) * K + colb;
  const int8_t* gB0 = B + (size_t)(n0 + row) * K + colb;
  const int8_t* gB1 = B + (size_t)(n0 + row + 64) * K + colb;
  int8_t* lA0 = As + tid * 16;
  int8_t* lA1 = As + 4096 + tid * 16;
  int8_t* lB0 = Bs + tid * 16;
  int8_t* lB1 = Bs + 4096 + tid * 16;

  const int afrag = (wr * 64 + (lane & 15)) * 64 + (lane >> 4) * 16;  // + mt*16*64
  const int bfrag = (wc * 64 + (lane & 15)) * 64 + (lane >> 4) * 16;  // + nt*16*64

  for (int k0 = 0; k0 < K; k0 += 64) {
    async_ld16(gA0 + k0, lA0);
    async_ld16(gA1 + k0, lA1);
    async_ld16(gB0 + k0, lB0);
    async_ld16(gB1 + k0, lB1);
    __syncthreads();
    v4i a[4], b[4];
    #pragma unroll
    for (int mt = 0; mt < 4; ++mt) a[mt] = *(const v4i*)(As + afrag + mt * 1024);
    #pragma unroll
    for (int nt = 0; nt < 4; ++nt) b[nt] = *(const v4i*)(Bs + bfrag + nt * 1024);
    #pragma unroll
    for (int mt = 0; mt < 4; ++mt)
      #pragma unroll
      for (int nt = 0; nt < 4; ++nt)
        acc[mt][nt] = __builtin_amdgcn_mfma_i32_16x16x64_i8(a[mt], b[nt], acc[mt][nt], 0, 0, 0);
    __syncthreads();
  }

  const float wscale = (float)fmax(wsum[0] * invcnt, (double)EPSQ);
  // C/D layout (16x16): col = lane&15, row = (lane>>4)*4 + reg
  #pragma unroll
  for (int mt = 0; mt < 4; ++mt) {
    const int trow = m0 + wr * 64 + mt * 16 + (lane >> 4) * 4;
    float fr[4];
    #pragma unroll
    for (int r = 0; r < 4; ++r) fr[r] = wscale * invs[trow + r];
    const int col = n0 + wc * 64 + (lane & 15);
    #pragma unroll
    for (int nt = 0; nt < 4; ++nt) {
      #pragma unroll
      for (int r = 0; r < 4; ++r) {
        float v = (float)acc[mt][nt][r] * fr[r];
        if (RELU2) v = v > 0.f ? v * v : 0.f;
        C[(size_t)(trow + r) * N + (col + nt * 16)] = v;
      }
    }
  }
}

extern "C" void kernel_launch(void* const* d_in, const int* in_sizes, int n_in,
                              void* d_out, int out_size, void* d_ws, size_t ws_size,
                              hipStream_t stream) {
  const float* x      = (const float*)d_in[0];   // (4,4096,2048)
  const float* w_up   = (const float*)d_in[1];   // (4096,2048)
  const float* w_down = (const float*)d_in[2];   // (2048,4096)
  float* out = (float*)d_out;

  const int T = in_sizes[0] / HIDDEN;            // 16384 tokens
  const size_t WN = (size_t)INTER * HIDDEN;      // 8388608 weights per matrix

  char* ws = (char*)d_ws;
  double* sums   = (double*)ws;                                   // [2]
  float* invs1   = (float*)(ws + 256);                            // [T]
  float* invs2   = (float*)(ws + 256 + 65536);                    // [T]
  int8_t* wq_up  = (int8_t*)(ws + 131328);                        // 8 MB
  int8_t* wq_dn  = wq_up + WN;                                    // 8 MB
  int8_t* a8_1   = wq_dn + WN;                                    // T*2048
  int8_t* a8_2   = a8_1 + (size_t)T * HIDDEN;                     // T*4096
  float*  h      = (float*)(a8_2 + (size_t)T * INTER);            // T*4096 f32

  const double invcnt = 1.0 / (double)WN;

  hipMemsetAsync(sums, 0, 256, stream);
  absmean_kernel<<<1024, 256, 0, stream>>>(w_up, WN / 4, sums + 0);
  absmean_kernel<<<1024, 256, 0, stream>>>(w_down, WN / 4, sums + 1);
  quantw_kernel<<<2048, 256, 0, stream>>>(w_up, WN / 4, sums + 0, invcnt, wq_up);
  quantw_kernel<<<2048, 256, 0, stream>>>(w_down, WN / 4, sums + 1, invcnt, wq_dn);

  fwht_quant_kernel<11><<<T, 256, 0, stream>>>(x, a8_1, invs1);
  gemm_i8_kernel<true><<<dim3(INTER / 128, T / 128), 256, 0, stream>>>(
      a8_1, wq_up, h, invs1, sums + 0, invcnt, INTER, HIDDEN);
  fwht_quant_kernel<12><<<T, 256, 0, stream>>>(h, a8_2, invs2);
  gemm_i8_kernel<false><<<dim3(HIDDEN / 128, T / 128), 256, 0, stream>>>(
      a8_2, wq_dn, out, invs2, sums + 1, invcnt, HIDDEN, INTER);
}

// Round 2
// 696.451 us; speedup vs baseline: 1.1152x; 1.1152x over previous
//
#include <hip/hip_runtime.h>
#include <hip/hip_fp16.h>
#include <cstdint>
#include <cstddef>

#define HIDDEN 2048
#define INTER  4096
#define EPSQ   1e-5f

typedef int v4i __attribute__((ext_vector_type(4)));

__device__ __forceinline__ void async_ld16(const void* g, void* l) {
  __builtin_amdgcn_global_load_lds((const __attribute__((address_space(1))) void*)g,
                                   (__attribute__((address_space(3))) void*)l, 16, 0, 0);
}

// ---------------- absmean reduction (f64 accumulate, atomic combine) ----------------
__global__ void absmean_kernel(const float* __restrict__ w, size_t n4, double* __restrict__ out) {
  double s = 0.0;
  const float4* w4 = (const float4*)w;
  for (size_t i = blockIdx.x * (size_t)blockDim.x + threadIdx.x; i < n4;
       i += (size_t)gridDim.x * blockDim.x) {
    float4 v = w4[i];
    s += (double)fabsf(v.x) + (double)fabsf(v.y) + (double)fabsf(v.z) + (double)fabsf(v.w);
  }
  #pragma unroll
  for (int o = 32; o; o >>= 1) s += __shfl_down(s, o);
  __shared__ double red[4];
  if ((threadIdx.x & 63) == 0) red[threadIdx.x >> 6] = s;
  __syncthreads();
  if (threadIdx.x == 0) atomicAdd(out, red[0] + red[1] + red[2] + red[3]);
}

// ---------------- weight ternarization: q = clip(round(w/scale), -1, 1) ----------------
__global__ void quantw_kernel(const float* __restrict__ w, size_t n4,
                              const double* __restrict__ sum, double invcnt,
                              int8_t* __restrict__ q) {
  const float scale = (float)fmax(sum[0] * invcnt, (double)EPSQ);
  const float4* w4 = (const float4*)w;
  char4* q4 = (char4*)q;
  for (size_t i = blockIdx.x * (size_t)blockDim.x + threadIdx.x; i < n4;
       i += (size_t)gridDim.x * blockDim.x) {
    float4 v = w4[i];
    char4 c;
    c.x = (signed char)fmaxf(-1.f, fminf(1.f, rintf(v.x / scale)));
    c.y = (signed char)fmaxf(-1.f, fminf(1.f, rintf(v.y / scale)));
    c.z = (signed char)fmaxf(-1.f, fminf(1.f, rintf(v.z / scale)));
    c.w = (signed char)fmaxf(-1.f, fminf(1.f, rintf(v.w / scale)));
    q4[i] = c;
  }
}

// ---------------- FWHT: one wave per token, H_N = H_E(regs) (x) H_64(lanes) ----------------
// Element i = lane*E + e. In-register stages cover bits 0..log2(E)-1, shuffle stages
// cover lane bits. Normalization folds into the quant scale (cancels in q).
template <int LOGN, bool HALF_IN>
__global__ void __launch_bounds__(256) fwht_quant_kernel(const void* __restrict__ Xv,
                                                         int8_t* __restrict__ Q,
                                                         float* __restrict__ invs) {
  constexpr int N = 1 << LOGN;
  constexpr int E = N / 64;                     // 32 (2048) or 64 (4096) regs/lane
  const int lane = threadIdx.x & 63;
  const size_t t = (size_t)blockIdx.x * 4 + (threadIdx.x >> 6);

  float r[E];
  if constexpr (HALF_IN) {
    const int4* xp = (const int4*)((const __half*)Xv + t * (size_t)N + lane * E);
    #pragma unroll
    for (int u = 0; u < E / 8; ++u) {
      alignas(16) __half hb[8];
      *(int4*)hb = xp[u];
      #pragma unroll
      for (int j = 0; j < 8; ++j) r[u * 8 + j] = __half2float(hb[j]);
    }
  } else {
    const float4* xp = (const float4*)((const float*)Xv + t * (size_t)N + lane * E);
    #pragma unroll
    for (int u = 0; u < E / 4; ++u) {
      float4 v = xp[u];
      r[u * 4 + 0] = v.x; r[u * 4 + 1] = v.y; r[u * 4 + 2] = v.z; r[u * 4 + 3] = v.w;
    }
  }

  // in-register butterfly stages (bits within e)
  #pragma unroll
  for (int m = 1; m < E; m <<= 1) {
    #pragma unroll
    for (int e = 0; e < E; ++e) {
      if (!(e & m)) {
        float a = r[e], b = r[e | m];
        r[e] = a + b;
        r[e | m] = a - b;
      }
    }
  }
  // cross-lane butterfly stages (lane bits), via ds_bpermute shuffles
  #pragma unroll
  for (int m = 1; m < 64; m <<= 1) {
    const float sgn = (lane & m) ? -1.f : 1.f;
    #pragma unroll
    for (int e = 0; e < E; ++e) {
      float w = __shfl_xor(r[e], m, 64);
      r[e] = fmaf(r[e], sgn, w);   // lower lane: v+w ; upper lane: w-v
    }
  }

  // absmax over token (unnormalized), then fold 1/sqrt(N) into scale
  float mx = 0.f;
  #pragma unroll
  for (int e = 0; e < E; ++e) mx = fmaxf(mx, fabsf(r[e]));
  #pragma unroll
  for (int m = 1; m < 64; m <<= 1) mx = fmaxf(mx, __shfl_xor(mx, m, 64));

  constexpr float c = (LOGN == 11) ? 0.022097086912079608f : 0.015625f;  // 1/sqrt(N)
  mx = fmaxf(mx * c, EPSQ);                    // clip(max|fwht(x)|, EPS)
  const float sc = 127.0f * c / mx;            // q = round(r * c * 127/mx)
  if (lane == 0) invs[t] = mx * (1.0f / 127.0f);

  alignas(16) int8_t qv[E];
  #pragma unroll
  for (int e = 0; e < E; ++e) {
    float q = rintf(r[e] * sc);
    q = fmaxf(-127.f, fminf(127.f, q));
    qv[e] = (int8_t)q;
  }
  int8_t* qp = Q + t * (size_t)N + lane * E;
  #pragma unroll
  for (int u = 0; u < E / 16; ++u) ((int4*)qp)[u] = ((const int4*)qv)[u];
}

// ---------------- int8 GEMM: C[t,n] = epilogue( sum_k A[t,k]*B[n,k] ) ----------------
// 128x128 tile, BK=64 bytes, 256 threads = 4 waves (2x2), each wave 64x64 via 4x4 mfma 16x16x64.
template <bool RELU2, typename TOUT>
__global__ void gemm_i8_kernel(const int8_t* __restrict__ A, const int8_t* __restrict__ B,
                               TOUT* __restrict__ C, const float* __restrict__ invs,
                               const double* __restrict__ wsum, double invcnt,
                               int N, int K) {
  __shared__ int8_t As[128 * 64];
  __shared__ int8_t Bs[128 * 64];
  const int tid = threadIdx.x;
  const int lane = tid & 63, wave = tid >> 6;
  const int wr = wave >> 1, wc = wave & 1;
  const int m0 = blockIdx.y * 128, n0 = blockIdx.x * 128;

  v4i acc[4][4] = {};

  const int row = tid >> 2;
  const int colb = (tid & 3) * 16;
  const int8_t* gA0 = A + (size_t)(m0 + row) * K + colb;
  const int8_t* gA1 = A + (size_t)(m0 + row + 64) * K + colb;
  const int8_t* gB0 = B + (size_t)(n0 + row) * K + colb;
  const int8_t* gB1 = B + (size_t)(n0 + row + 64) * K + colb;
  int8_t* lA0 = As + tid * 16;
  int8_t* lA1 = As + 4096 + tid * 16;
  int8_t* lB0 = Bs + tid * 16;
  int8_t* lB1 = Bs + 4096 + tid * 16;

  const int afrag = (wr * 64 + (lane & 15)) * 64 + (lane >> 4) * 16;  // + mt*16*64
  const int bfrag = (wc * 64 + (lane & 15)) * 64 + (lane >> 4) * 16;  // + nt*16*64

  for (int k0 = 0; k0 < K; k0 += 64) {
    async_ld16(gA0 + k0, lA0);
    async_ld16(gA1 + k0, lA1);
    async_ld16(gB0 + k0, lB0);
    async_ld16(gB1 + k0, lB1);
    __syncthreads();
    v4i a[4], b[4];
    #pragma unroll
    for (int mt = 0; mt < 4; ++mt) a[mt] = *(const v4i*)(As + afrag + mt * 1024);
    #pragma unroll
    for (int nt = 0; nt < 4; ++nt) b[nt] = *(const v4i*)(Bs + bfrag + nt * 1024);
    #pragma unroll
    for (int mt = 0; mt < 4; ++mt)
      #pragma unroll
      for (int nt = 0; nt < 4; ++nt)
        acc[mt][nt] = __builtin_amdgcn_mfma_i32_16x16x64_i8(a[mt], b[nt], acc[mt][nt], 0, 0, 0);
    __syncthreads();
  }

  const float wscale = (float)fmax(wsum[0] * invcnt, (double)EPSQ);
  // C/D layout (16x16): col = lane&15, row = (lane>>4)*4 + reg
  #pragma unroll
  for (int mt = 0; mt < 4; ++mt) {
    const int trow = m0 + wr * 64 + mt * 16 + (lane >> 4) * 4;
    float fr[4];
    #pragma unroll
    for (int r = 0; r < 4; ++r) fr[r] = wscale * invs[trow + r];
    const int col = n0 + wc * 64 + (lane & 15);
    #pragma unroll
    for (int nt = 0; nt < 4; ++nt) {
      #pragma unroll
      for (int r = 0; r < 4; ++r) {
        float v = (float)acc[mt][nt][r] * fr[r];
        if (RELU2) v = v > 0.f ? v * v : 0.f;
        if constexpr (sizeof(TOUT) == 2)
          C[(size_t)(trow + r) * N + (col + nt * 16)] = __float2half(v);
        else
          C[(size_t)(trow + r) * N + (col + nt * 16)] = v;
      }
    }
  }
}

extern "C" void kernel_launch(void* const* d_in, const int* in_sizes, int n_in,
                              void* d_out, int out_size, void* d_ws, size_t ws_size,
                              hipStream_t stream) {
  const float* x      = (const float*)d_in[0];   // (4,4096,2048)
  const float* w_up   = (const float*)d_in[1];   // (4096,2048)
  const float* w_down = (const float*)d_in[2];   // (2048,4096)
  float* out = (float*)d_out;

  const int T = in_sizes[0] / HIDDEN;            // 16384 tokens
  const size_t WN = (size_t)INTER * HIDDEN;      // 8388608 weights per matrix

  char* ws = (char*)d_ws;
  double* sums   = (double*)ws;                                   // [2]
  float* invs1   = (float*)(ws + 256);                            // [T]
  float* invs2   = (float*)(ws + 256 + 65536);                    // [T]
  int8_t* wq_up  = (int8_t*)(ws + 131328);                        // 8 MB
  int8_t* wq_dn  = wq_up + WN;                                    // 8 MB
  int8_t* a8_1   = wq_dn + WN;                                    // T*2048
  int8_t* a8_2   = a8_1 + (size_t)T * HIDDEN;                     // T*4096
  __half* h      = (__half*)(a8_2 + (size_t)T * INTER);           // T*4096 fp16

  const double invcnt = 1.0 / (double)WN;

  hipMemsetAsync(sums, 0, 256, stream);
  absmean_kernel<<<1024, 256, 0, stream>>>(w_up, WN / 4, sums + 0);
  absmean_kernel<<<1024, 256, 0, stream>>>(w_down, WN / 4, sums + 1);
  quantw_kernel<<<2048, 256, 0, stream>>>(w_up, WN / 4, sums + 0, invcnt, wq_up);
  quantw_kernel<<<2048, 256, 0, stream>>>(w_down, WN / 4, sums + 1, invcnt, wq_dn);

  fwht_quant_kernel<11, false><<<T / 4, 256, 0, stream>>>(x, a8_1, invs1);
  gemm_i8_kernel<true, __half><<<dim3(INTER / 128, T / 128), 256, 0, stream>>>(
      a8_1, wq_up, h, invs1, sums + 0, invcnt, INTER, HIDDEN);
  fwht_quant_kernel<12, true><<<T / 4, 256, 0, stream>>>(h, a8_2, invs2);
  gemm_i8_kernel<false, float><<<dim3(HIDDEN / 128, T / 128), 256, 0, stream>>>(
      a8_2, wq_dn, out, invs2, sums + 1, invcnt, HIDDEN, INTER);
}